// Round 1
// baseline (4545.174 us; speedup 1.0000x reference)
//
#include <hip/hip_runtime.h>

#define Bc 4
#define Tc 500
#define Uc 100
#define Dc 512
#define Hc 512
#define Vc 64
#define G4 2048
#define NB 128

__device__ __forceinline__ float fsig(float x) {
  return __builtin_amdgcn_rcpf(1.f + __expf(-x));
}
__device__ __forceinline__ float ftanh(float x) {
  float e = __expf(2.f * x);
  return 1.f - 2.f * __builtin_amdgcn_rcpf(e + 1.f);
}

// C[n][m] = sum_k A[n][k] * Bw[m*ldb + k] + bias[m] + bias2[m]
// If ids != null, A-row n is emb[ids[n]] (embedding fused, row stride 512).
// K fixed at 512. M multiple of 64. N guarded.
__global__ __launch_bounds__(256) void k_gemm(
    const float* __restrict__ A, int lda,
    const float* __restrict__ Bw, int ldb,
    const float* __restrict__ bias, const float* __restrict__ bias2,
    float* __restrict__ C, int ldc, int N,
    const int* __restrict__ ids, const float* __restrict__ emb)
{
  __shared__ float As[16][65];
  __shared__ float Bs[16][65];
  const int tid = threadIdx.x;
  const int tx = tid & 15, ty = tid >> 4;
  const int m0 = blockIdx.x * 64, n0 = blockIdx.y * 64;
  float acc[4][4] = {};
  for (int k0 = 0; k0 < 512; k0 += 16) {
#pragma unroll
    for (int i = 0; i < 4; ++i) {
      int n = n0 + ty + 16 * i;
      float av = 0.f;
      if (n < N) {
        const float* ar = ids ? (emb + (long)ids[n] * 512) : (A + (long)n * lda);
        av = ar[k0 + tx];
      }
      As[tx][ty + 16 * i] = av;
      Bs[tx][ty + 16 * i] = Bw[(long)(m0 + ty + 16 * i) * ldb + k0 + tx];
    }
    __syncthreads();
#pragma unroll
    for (int kl = 0; kl < 16; ++kl) {
      float a[4], b[4];
#pragma unroll
      for (int i = 0; i < 4; ++i) a[i] = As[kl][ty * 4 + i];
#pragma unroll
      for (int j = 0; j < 4; ++j) b[j] = Bs[kl][tx * 4 + j];
#pragma unroll
      for (int i = 0; i < 4; ++i)
#pragma unroll
        for (int j = 0; j < 4; ++j) acc[i][j] += a[i] * b[j];
    }
    __syncthreads();
  }
#pragma unroll
  for (int i = 0; i < 4; ++i) {
    int n = n0 + ty * 4 + i;
    if (n >= N) continue;
#pragma unroll
    for (int j = 0; j < 4; ++j) {
      int m = m0 + tx * 4 + j;
      float v = acc[i][j];
      if (bias)  v += bias[m];
      if (bias2) v += bias2[m];
      C[(long)n * ldc + m] = v;
    }
  }
}

// Persistent LSTM recurrence for one layer. NB blocks, each owns 4 hidden
// units (16 gate rows). w_hh slice lives in LDS with a per-row rotation
// (store col (k+4r)&511) so the wave's b128 reads hit each bank exactly
// 8 words -> conflict-free. Per step: stage h to LDS, dot, activations,
// then a monotonic device-scope atomic barrier (ctr zeroed by memset).
__global__ __launch_bounds__(256) void k_rec(
    const float* __restrict__ ixp,   // (B*U, 2048) x@w_ih.T + b_ih + b_hh
    const float* __restrict__ whh,   // (2048, 512) this layer
    float* __restrict__ ys,          // (B,U,H) h outputs per step
    float* __restrict__ hbuf,        // double buffer 2*B*H
    float* __restrict__ hout, float* __restrict__ cout_,  // final h,c (B,H)
    int* __restrict__ ctr)
{
  __shared__ float wl[16 * 512];
  __shared__ float hl[4 * 512];
  __shared__ float gbuf[64];
  __shared__ float cbuf[16];
  const int tid = threadIdx.x;
  const int blk = blockIdx.x;
  const int u0 = blk * 4;
  for (int idx = tid; idx < 16 * 512; idx += 256) {
    int r = idx >> 9, k = idx & 511;
    int q = r >> 2, uu = r & 3;
    int grow = q * 512 + u0 + uu;
    wl[r * 512 + ((k + 4 * r) & 511)] = whh[(long)grow * 512 + k];
  }
  if (tid < 16) cbuf[tid] = 0.f;
  __syncthreads();

  const int kq = tid & 3;          // k quarter (128 each)
  const int r = (tid >> 2) & 15;   // local gate row
  const int b = tid >> 6;          // batch = wave
  const int rot = 4 * r;
  const int kbase = kq * 128;

  for (int s = 0; s < Uc; ++s) {
    if (s > 0) {
      const float4* hp = (const float4*)(hbuf + (s & 1) * 2048);
      float4* hl4 = (float4*)hl;
      for (int idx = tid; idx < 512; idx += 256) hl4[idx] = hp[idx];
      __syncthreads();
      float a = 0.f;
#pragma unroll 8
      for (int j = 0; j < 32; ++j) {
        int k = kbase + 4 * j;
        int wi = (k + rot) & 511;
        float4 w4 = *(const float4*)&wl[r * 512 + wi];
        float4 h4 = *(const float4*)&hl[b * 512 + k];
        a += w4.x * h4.x + w4.y * h4.y + w4.z * h4.z + w4.w * h4.w;
      }
      a += __shfl_xor(a, 1);
      a += __shfl_xor(a, 2);
      if (kq == 0) gbuf[b * 16 + r] = a;
      __syncthreads();
    }
    if (tid < 16) {
      const int ub = tid >> 2, uu = tid & 3;
      const float* ixrow = ixp + (long)(ub * Uc + s) * G4 + u0 + uu;
      float gi = ixrow[0];
      float gf = ixrow[512];
      float gg = ixrow[1024];
      float go = ixrow[1536];
      if (s > 0) {
        gi += gbuf[ub * 16 + 0  + uu];
        gf += gbuf[ub * 16 + 4  + uu];
        gg += gbuf[ub * 16 + 8  + uu];
        go += gbuf[ub * 16 + 12 + uu];
      }
      float c = cbuf[tid];
      float cn = fsig(gf) * c + fsig(gi) * ftanh(gg);
      float hn = fsig(go) * ftanh(cn);
      cbuf[tid] = cn;
      hbuf[((s + 1) & 1) * 2048 + ub * 512 + u0 + uu] = hn;
      ys[(long)(ub * Uc + s) * 512 + u0 + uu] = hn;
      if (s == Uc - 1) {
        hout[ub * 512 + u0 + uu] = hn;
        cout_[ub * 512 + u0 + uu] = cn;
      }
    }
    if (s < Uc - 1) {
      __threadfence();
      __syncthreads();
      if (tid == 0) {
        __hip_atomic_fetch_add(ctr, 1, __ATOMIC_RELEASE, __HIP_MEMORY_SCOPE_AGENT);
        const int target = NB * (s + 1);
        while (__hip_atomic_load(ctr, __ATOMIC_ACQUIRE, __HIP_MEMORY_SCOPE_AGENT) < target)
          __builtin_amdgcn_s_sleep(1);
      }
      __syncthreads();
    }
  }
}

// Fused joint: out[b,t,u,v] = sum_h tanh(enc[b,t,h]+dec[b,u,h])*jw2[v,h] + jb2[v]
// (jb1 is pre-folded into dec). Block = (b, 4 t's); jw2 in VGPRs (64/lane):
// lane (vg,pw) of wave w owns v in {vg+8j} over k-slice [ (w*8+pw)*8, +8 ).
__global__ __launch_bounds__(512) void k_joint(
    const float* __restrict__ enc,   // (B*T, 512)
    const float* __restrict__ dec,   // (B*U, 512), includes jb1
    const float* __restrict__ jw2,   // (64, 512)
    const float* __restrict__ jb2,   // (64)
    float* __restrict__ out)         // (B,T,U,64)
{
  __shared__ float th[512];
  __shared__ float red[512];
  __shared__ float el[4 * 512];
  const int tid = threadIdx.x;
  const int blk = blockIdx.x;
  const int bb = blk / 125;
  const int t0 = (blk % 125) * 4;
  const int wave = tid >> 6, lane = tid & 63;
  const int vg = lane & 7, pw = lane >> 3;
  const int kb = (wave * 8 + pw) * 8;
  float w2r[8][8];
#pragma unroll
  for (int j = 0; j < 8; ++j) {
    const float* wp = jw2 + (vg + 8 * j) * 512 + kb;
    float4 x0 = *(const float4*)wp;
    float4 x1 = *(const float4*)(wp + 4);
    w2r[j][0] = x0.x; w2r[j][1] = x0.y; w2r[j][2] = x0.z; w2r[j][3] = x0.w;
    w2r[j][4] = x1.x; w2r[j][5] = x1.y; w2r[j][6] = x1.z; w2r[j][7] = x1.w;
  }
  for (int ii = tid; ii < 4 * 512; ii += 512)
    el[ii] = enc[(long)(bb * Tc + t0 + (ii >> 9)) * 512 + (ii & 511)];
  __syncthreads();
  for (int tt = 0; tt < 4; ++tt) {
    const int t = t0 + tt;
    for (int u = 0; u < Uc; ++u) {
      th[tid] = ftanh(el[tt * 512 + tid] + dec[(long)(bb * Uc + u) * 512 + tid]);
      __syncthreads();
      float4 a0 = *(const float4*)&th[kb];
      float4 a1 = *(const float4*)&th[kb + 4];
      float acc[8];
#pragma unroll
      for (int j = 0; j < 8; ++j)
        acc[j] = w2r[j][0] * a0.x + w2r[j][1] * a0.y + w2r[j][2] * a0.z + w2r[j][3] * a0.w
               + w2r[j][4] * a1.x + w2r[j][5] * a1.y + w2r[j][6] * a1.z + w2r[j][7] * a1.w;
#pragma unroll
      for (int j = 0; j < 8; ++j) {
        acc[j] += __shfl_xor(acc[j], 8);
        acc[j] += __shfl_xor(acc[j], 16);
        acc[j] += __shfl_xor(acc[j], 32);
      }
      if (pw == 0) {
        float4 r0 = make_float4(acc[0], acc[1], acc[2], acc[3]);
        float4 r1 = make_float4(acc[4], acc[5], acc[6], acc[7]);
        *(float4*)&red[wave * 64 + vg * 8] = r0;
        *(float4*)&red[wave * 64 + vg * 8 + 4] = r1;
      }
      __syncthreads();
      if (tid < 64) {
        const int o = (tid & 7) * 8 + (tid >> 3);
        float sum = jb2[tid];
#pragma unroll
        for (int w = 0; w < 8; ++w) sum += red[w * 64 + o];
        out[(long)((bb * Tc + t) * Uc + u) * Vc + tid] = sum;
      }
      __syncthreads();
    }
  }
}

extern "C" void kernel_launch(void* const* d_in, const int* in_sizes, int n_in,
                              void* d_out, int out_size, void* d_ws, size_t ws_size,
                              hipStream_t stream)
{
  const int*   ids    = (const int*)d_in[0];
  const float* memory = (const float*)d_in[1];
  const float* emb    = (const float*)d_in[2];
  const float* w_ih   = (const float*)d_in[3];
  const float* w_hh   = (const float*)d_in[4];
  const float* b_ih   = (const float*)d_in[5];
  const float* b_hh   = (const float*)d_in[6];
  const float* fc_w   = (const float*)d_in[7];
  const float* fc_b   = (const float*)d_in[8];
  const float* jw1    = (const float*)d_in[9];
  const float* jb1    = (const float*)d_in[10];
  const float* jw2    = (const float*)d_in[11];
  const float* jb2    = (const float*)d_in[12];
  float* out = (float*)d_out;

  float* wsf  = (float*)d_ws;
  int*   ctr0 = (int*)d_ws;        // byte 0
  int*   ctr1 = ctr0 + 32;         // byte 128
  float* hbuf = wsf + 128;                 // 2*B*H = 4096
  float* ixp  = hbuf + 2 * Bc * Hc;        // B*U*4H = 819200
  float* ys1  = ixp + (long)Bc * Uc * G4;  // 204800
  float* ys2  = ys1 + Bc * Uc * Hc;        // 204800
  float* xfc  = ys2 + Bc * Uc * Hc;        // 204800
  float* decb = xfc + Bc * Uc * Hc;        // 204800
  float* encb = decb + Bc * Uc * Hc;       // B*T*H = 1024000

  float* hO = out + (long)Bc * Tc * Uc * Vc;  // 12800000
  float* cO = hO + 2 * Bc * Hc;               // + L*B*H = 4096

  // zero the barrier counters every call (graph replay safe)
  hipMemsetAsync(d_ws, 0, 512, stream);

  // layer 0 input projection (embedding fused)
  k_gemm<<<dim3(32, 7), 256, 0, stream>>>(nullptr, 0, w_ih, 512, b_ih, b_hh,
                                          ixp, G4, Bc * Uc, ids, emb);
  k_rec<<<NB, 256, 0, stream>>>(ixp, w_hh, ys1, hbuf, hO, cO, ctr0);
  // layer 1 input projection
  k_gemm<<<dim3(32, 7), 256, 0, stream>>>(ys1, 512, w_ih + (long)G4 * 512, 512,
                                          b_ih + G4, b_hh + G4, ixp, G4, Bc * Uc,
                                          nullptr, nullptr);
  k_rec<<<NB, 256, 0, stream>>>(ixp, w_hh + (long)G4 * 512, ys2, hbuf,
                                hO + Bc * Hc, cO + Bc * Hc, ctr1);
  // fc: xfc = ys2 @ fc_w.T + fc_b
  k_gemm<<<dim3(8, 7), 256, 0, stream>>>(ys2, 512, fc_w, 512, fc_b, nullptr,
                                         xfc, 512, Bc * Uc, nullptr, nullptr);
  // dec_p = xfc @ wd.T + jb1   (wd = jw1[:, 512:], row stride 1024)
  k_gemm<<<dim3(8, 7), 256, 0, stream>>>(xfc, 512, jw1 + 512, 1024, jb1, nullptr,
                                         decb, 512, Bc * Uc, nullptr, nullptr);
  // enc_p = memory @ we.T      (we = jw1[:, :512])
  k_gemm<<<dim3(8, 32), 256, 0, stream>>>(memory, 512, jw1, 1024, nullptr, nullptr,
                                          encb, 512, Bc * Tc, nullptr, nullptr);
  // fused joint
  k_joint<<<500, 512, 0, stream>>>(encb, decb, jw2, jb2, out);
}

// Round 2
// 1976.016 us; speedup vs baseline: 2.3002x; 2.3002x over previous
//
#include <hip/hip_runtime.h>

#define Bc 4
#define Tc 500
#define Uc 100
#define Vc 64
#define G4 2048
#define NBR 96   // 32 layer-0 blocks + 64 layer-1 blocks

__device__ __forceinline__ float fsig(float x) {
  return __builtin_amdgcn_rcpf(1.f + __expf(-x));
}
__device__ __forceinline__ float ftanh(float x) {
  float e = __expf(2.f * x);
  return 1.f - 2.f * __builtin_amdgcn_rcpf(e + 1.f);
}

// C[n][m] = sum_k A[n][k] * Bw[m*ldb + k] + bias[m] + bias2[m]
// If ids != null, A-row n is emb[ids[n]] (embedding fused). K fixed 512.
__global__ __launch_bounds__(256) void k_gemm(
    const float* __restrict__ A, int lda,
    const float* __restrict__ Bw, int ldb,
    const float* __restrict__ bias, const float* __restrict__ bias2,
    float* __restrict__ C, int ldc, int N,
    const int* __restrict__ ids, const float* __restrict__ emb)
{
  __shared__ float As[16][65];
  __shared__ float Bs[16][65];
  const int tid = threadIdx.x;
  const int tx = tid & 15, ty = tid >> 4;
  const int m0 = blockIdx.x * 64, n0 = blockIdx.y * 64;
  float acc[4][4] = {};
  for (int k0 = 0; k0 < 512; k0 += 16) {
#pragma unroll
    for (int i = 0; i < 4; ++i) {
      int n = n0 + ty + 16 * i;
      float av = 0.f;
      if (n < N) {
        const float* ar = ids ? (emb + (long)ids[n] * 512) : (A + (long)n * lda);
        av = ar[k0 + tx];
      }
      As[tx][ty + 16 * i] = av;
      Bs[tx][ty + 16 * i] = Bw[(long)(m0 + ty + 16 * i) * ldb + k0 + tx];
    }
    __syncthreads();
#pragma unroll
    for (int kl = 0; kl < 16; ++kl) {
      float a[4], b[4];
#pragma unroll
      for (int i = 0; i < 4; ++i) a[i] = As[kl][ty * 4 + i];
#pragma unroll
      for (int j = 0; j < 4; ++j) b[j] = Bs[kl][tx * 4 + j];
#pragma unroll
      for (int i = 0; i < 4; ++i)
#pragma unroll
        for (int j = 0; j < 4; ++j) acc[i][j] += a[i] * b[j];
    }
    __syncthreads();
  }
#pragma unroll
  for (int i = 0; i < 4; ++i) {
    int n = n0 + ty * 4 + i;
    if (n >= N) continue;
#pragma unroll
    for (int j = 0; j < 4; ++j) {
      int m = m0 + tx * 4 + j;
      float v = acc[i][j];
      if (bias)  v += bias[m];
      if (bias2) v += bias2[m];
      C[(long)n * ldc + m] = v;
    }
  }
}

// Pipelined 2-layer LSTM recurrence. 96 blocks:
//   blk 0..31  : layer 0, 16 hidden units each; weights = w_hh0 rows (64) in VGPRs.
//   blk 32..95 : layer 1,  8 hidden units each; weights = w_ih1 rows (32) +
//                w_hh1 rows (32) in VGPRs (input projection computed on the fly).
// Global step g: L0 computes h0[g] (g<=99); L1 computes h1[g-1] (g>=1).
// h exchanged via hbuf double buffer; flag-array barrier (no atomic RMW).
__global__ __launch_bounds__(256, 1) void k_rec2(
    const float* __restrict__ ixp0,   // (B*U, 2048) = x0 @ w_ih0.T + b_ih0 + b_hh0
    const float* __restrict__ wih1,   // (2048, 512)
    const float* __restrict__ whh0,   // (2048, 512)
    const float* __restrict__ whh1,   // (2048, 512)
    const float* __restrict__ bih1,   // (2048)
    const float* __restrict__ bhh1,   // (2048)
    float* __restrict__ ys2,          // (B,U,512) layer-1 outputs
    float* __restrict__ hbuf,         // 2 slots * (h0:4*512, h1:4*512), zeroed
    float* __restrict__ hO, float* __restrict__ cO,  // (2,B,512)
    int* __restrict__ flags)          // 128 ints, zeroed
{
  __shared__ float4 hl4[2 * 4 * 128];  // [src][b][quad] swizzled: quad c*8+((o+c)&7)
  __shared__ float4 red4[256];         // [wave][rg][r] -> float4 over b
  const int tid = threadIdx.x;
  const int blk = blockIdx.x;
  const bool isL1 = blk >= 32;
  const int rg = tid & 15, ks = tid >> 4;
  const int lane = tid & 63, wv = tid >> 6;

  // weight preload: 4 rows x 32 k (8 float4) per thread -> 128 VGPRs
  float4 wr4[4][8];
#pragma unroll
  for (int r = 0; r < 4; ++r) {
    int lr = rg * 4 + r;
    const float* wsrc; int grow;
    if (!isL1) { int q = lr >> 4, uu = lr & 15; grow = q * 512 + blk * 16 + uu; wsrc = whh0; }
    else {
      int jb = blk - 32; int half = lr >> 5, q = (lr >> 3) & 3, uu = lr & 7;
      grow = q * 512 + jb * 8 + uu; wsrc = half ? whh1 : wih1;
    }
    const float4* wp = (const float4*)(wsrc + (long)grow * 512 + ks * 32);
#pragma unroll
    for (int jj = 0; jj < 8; ++jj) wr4[r][jj] = wp[jj];
  }

  // epilogue thread mapping: (unit, batch) pairs
  const int nu = isL1 ? 8 : 16;
  const bool eact = tid < nu * 4;
  const int euu = tid >> 2, eb = tid & 3;
  float creg = 0.f;
  float bgate[4] = {0.f, 0.f, 0.f, 0.f};
  if (isL1 && eact) {
#pragma unroll
    for (int q = 0; q < 4; ++q) {
      int grow = q * 512 + (blk - 32) * 8 + euu;
      bgate[q] = bih1[grow] + bhh1[grow];
    }
  }

  const int hsrc = (isL1 && rg >= 8) ? 1 : 0;
  const float* redf = (const float*)red4;

  for (int g = 0; g <= 100; ++g) {
    const bool act = isL1 ? (g >= 1) : (g < 100);
    const int s = isL1 ? g - 1 : g;
    const int slotR = (g + 1) & 1;
    const int slotW = g & 1;

    // prefetch ixp for this step (L0 only) - consumed after the dot
    float ixv[4] = {0.f, 0.f, 0.f, 0.f};
    if (!isL1 && act && eact) {
      const float* ib = ixp0 + ((long)(eb * Uc + s) * G4 + blk * 16 + euu);
#pragma unroll
      for (int q = 0; q < 4; ++q) ixv[q] = ib[q * 512];
    }

    // stage h into LDS (rotated-quad swizzle so k-slices hit distinct banks)
    {
      const float4* gh = (const float4*)(hbuf + slotR * 4096);
#pragma unroll
      for (int it = 0; it < 2; ++it) {
        int qd = tid + it * 256;
        int b = qd >> 7, kq = qd & 127;
        int c = kq >> 3, o = kq & 7;
        hl4[b * 128 + c * 8 + ((o + c) & 7)] = gh[qd];
      }
      if (isL1) {
#pragma unroll
        for (int it = 0; it < 2; ++it) {
          int qd = tid + it * 256;
          int b = qd >> 7, kq = qd & 127;
          int c = kq >> 3, o = kq & 7;
          hl4[512 + b * 128 + c * 8 + ((o + c) & 7)] = gh[512 + qd];
        }
      }
    }
    __syncthreads();

    float acc[4][4] = {};
    if (act) {
#pragma unroll
      for (int j = 0; j < 8; ++j) {
        int pq = hsrc * 512 + ks * 8 + ((j + ks) & 7);
        float4 h0q = hl4[pq];
        float4 h1q = hl4[pq + 128];
        float4 h2q = hl4[pq + 256];
        float4 h3q = hl4[pq + 384];
#pragma unroll
        for (int r = 0; r < 4; ++r) {
          float4 w = wr4[r][j];
          acc[r][0] += w.x * h0q.x + w.y * h0q.y + w.z * h0q.z + w.w * h0q.w;
          acc[r][1] += w.x * h1q.x + w.y * h1q.y + w.z * h1q.z + w.w * h1q.w;
          acc[r][2] += w.x * h2q.x + w.y * h2q.y + w.z * h2q.z + w.w * h2q.w;
          acc[r][3] += w.x * h3q.x + w.y * h3q.y + w.z * h3q.z + w.w * h3q.w;
        }
      }
      // reduce the 16 k-slices: 4 in-wave (lane bits 4..5), 4 across waves via LDS
#pragma unroll
      for (int r = 0; r < 4; ++r)
#pragma unroll
        for (int b = 0; b < 4; ++b) {
          float v = acc[r][b];
          v += __shfl_xor(v, 16);
          v += __shfl_xor(v, 32);
          acc[r][b] = v;
        }
      if (lane < 16) {
#pragma unroll
        for (int r = 0; r < 4; ++r)
          red4[wv * 64 + lane * 4 + r] =
              make_float4(acc[r][0], acc[r][1], acc[r][2], acc[r][3]);
      }
    }
    __syncthreads();

    if (act && eact) {
      float gv[4];
#pragma unroll
      for (int q = 0; q < 4; ++q) {
        float sv = 0.f;
        int lrA = isL1 ? (q * 8 + euu) : (q * 16 + euu);
#pragma unroll
        for (int w = 0; w < 4; ++w) sv += redf[(w * 64 + lrA) * 4 + eb];
        if (isL1) {
          int lrB = 32 + q * 8 + euu;
#pragma unroll
          for (int w = 0; w < 4; ++w) sv += redf[(w * 64 + lrB) * 4 + eb];
          sv += bgate[q];
        } else {
          sv += ixv[q];
        }
        gv[q] = sv;
      }
      float cn = fsig(gv[1]) * creg + fsig(gv[0]) * ftanh(gv[2]);
      float hn = fsig(gv[3]) * ftanh(cn);
      creg = cn;
      int gu = (isL1 ? (blk - 32) * 8 : blk * 16) + euu;
      hbuf[slotW * 4096 + (isL1 ? 2048 : 0) + eb * 512 + gu] = hn;
      if (isL1) ys2[((long)(eb * Uc + s)) * 512 + gu] = hn;
      if (s == Uc - 1) {
        hO[(isL1 ? 2048 : 0) + eb * 512 + gu] = hn;
        cO[(isL1 ? 2048 : 0) + eb * 512 + gu] = cn;
      }
    }

    // flag-array barrier (no RMW): store own flag, wave 0 polls all 96
    if (g < 100) {
      __syncthreads();  // drains this block's stores (vmcnt) before arrival
      if (tid == 0) {
        __builtin_amdgcn_fence(__ATOMIC_RELEASE, "agent");
        __hip_atomic_store(&flags[blk], g + 1, __ATOMIC_RELAXED,
                           __HIP_MEMORY_SCOPE_AGENT);
      }
      if (tid < 64) {
        const int tgt = g + 1;
        while (true) {
          int va = __hip_atomic_load(&flags[lane], __ATOMIC_RELAXED,
                                     __HIP_MEMORY_SCOPE_AGENT);
          int vb = (lane < 32)
                       ? __hip_atomic_load(&flags[64 + lane], __ATOMIC_RELAXED,
                                           __HIP_MEMORY_SCOPE_AGENT)
                       : tgt;
          if (__all(va >= tgt && vb >= tgt)) break;
          __builtin_amdgcn_s_sleep(2);
        }
        __builtin_amdgcn_fence(__ATOMIC_ACQUIRE, "agent");
      }
      __syncthreads();
    }
  }
}

// Fused joint: out[b,t,u,v] = sum_h tanh(enc[b,t,h]+dec[b,u,h])*jw2[v,h] + jb2[v]
__global__ __launch_bounds__(512) void k_joint(
    const float* __restrict__ enc,   // (B*T, 512)
    const float* __restrict__ dec,   // (B*U, 512), includes jb1
    const float* __restrict__ jw2,   // (64, 512)
    const float* __restrict__ jb2,   // (64)
    float* __restrict__ out)         // (B,T,U,64)
{
  __shared__ float th[512];
  __shared__ float red[512];
  __shared__ float el[4 * 512];
  const int tid = threadIdx.x;
  const int blk = blockIdx.x;
  const int bb = blk / 125;
  const int t0 = (blk % 125) * 4;
  const int wave = tid >> 6, lane = tid & 63;
  const int vg = lane & 7, pw = lane >> 3;
  const int kb = (wave * 8 + pw) * 8;
  float w2r[8][8];
#pragma unroll
  for (int j = 0; j < 8; ++j) {
    const float* wp = jw2 + (vg + 8 * j) * 512 + kb;
    float4 x0 = *(const float4*)wp;
    float4 x1 = *(const float4*)(wp + 4);
    w2r[j][0] = x0.x; w2r[j][1] = x0.y; w2r[j][2] = x0.z; w2r[j][3] = x0.w;
    w2r[j][4] = x1.x; w2r[j][5] = x1.y; w2r[j][6] = x1.z; w2r[j][7] = x1.w;
  }
  for (int ii = tid; ii < 4 * 512; ii += 512)
    el[ii] = enc[(long)(bb * Tc + t0 + (ii >> 9)) * 512 + (ii & 511)];
  __syncthreads();
  for (int tt = 0; tt < 4; ++tt) {
    const int t = t0 + tt;
    for (int u = 0; u < Uc; ++u) {
      th[tid] = ftanh(el[tt * 512 + tid] + dec[(long)(bb * Uc + u) * 512 + tid]);
      __syncthreads();
      float4 a0 = *(const float4*)&th[kb];
      float4 a1 = *(const float4*)&th[kb + 4];
      float acc[8];
#pragma unroll
      for (int j = 0; j < 8; ++j)
        acc[j] = w2r[j][0] * a0.x + w2r[j][1] * a0.y + w2r[j][2] * a0.z + w2r[j][3] * a0.w
               + w2r[j][4] * a1.x + w2r[j][5] * a1.y + w2r[j][6] * a1.z + w2r[j][7] * a1.w;
#pragma unroll
      for (int j = 0; j < 8; ++j) {
        acc[j] += __shfl_xor(acc[j], 8);
        acc[j] += __shfl_xor(acc[j], 16);
        acc[j] += __shfl_xor(acc[j], 32);
      }
      if (pw == 0) {
        *(float4*)&red[wave * 64 + vg * 8] = make_float4(acc[0], acc[1], acc[2], acc[3]);
        *(float4*)&red[wave * 64 + vg * 8 + 4] = make_float4(acc[4], acc[5], acc[6], acc[7]);
      }
      __syncthreads();
      if (tid < 64) {
        const int o = (tid & 7) * 8 + (tid >> 3);
        float sum = jb2[tid];
#pragma unroll
        for (int w = 0; w < 8; ++w) sum += red[w * 64 + o];
        out[(long)((bb * Tc + t) * Uc + u) * Vc + tid] = sum;
      }
      __syncthreads();
    }
  }
}

extern "C" void kernel_launch(void* const* d_in, const int* in_sizes, int n_in,
                              void* d_out, int out_size, void* d_ws, size_t ws_size,
                              hipStream_t stream)
{
  const int*   ids    = (const int*)d_in[0];
  const float* memory = (const float*)d_in[1];
  const float* emb    = (const float*)d_in[2];
  const float* w_ih   = (const float*)d_in[3];
  const float* w_hh   = (const float*)d_in[4];
  const float* b_ih   = (const float*)d_in[5];
  const float* b_hh   = (const float*)d_in[6];
  const float* fc_w   = (const float*)d_in[7];
  const float* fc_b   = (const float*)d_in[8];
  const float* jw1    = (const float*)d_in[9];
  const float* jb1    = (const float*)d_in[10];
  const float* jw2    = (const float*)d_in[11];
  const float* jb2    = (const float*)d_in[12];
  float* out = (float*)d_out;

  float* wsf   = (float*)d_ws;
  int*   flags = (int*)d_ws;               // 128 ints
  float* hbuf  = wsf + 128;                // 2*2*4*512 = 8192
  float* ixp0  = hbuf + 8192;              // B*U*4H = 819200
  float* ys2   = ixp0 + (long)Bc * Uc * G4;  // 204800
  float* xfc   = ys2 + Bc * Uc * 512;        // 204800
  float* decb  = xfc + Bc * Uc * 512;        // 204800
  float* encb  = decb + Bc * Uc * 512;       // B*T*H = 1024000

  float* hO = out + (long)Bc * Tc * Uc * Vc;
  float* cO = hO + 2 * Bc * 512;

  // zero flags + hbuf every call (graph-replay safe)
  hipMemsetAsync(d_ws, 0, 512 + 8192 * 4, stream);

  // layer-0 input projection (embedding fused): ixp0 = emb[ids] @ w_ih0.T + b0
  k_gemm<<<dim3(32, 7), 256, 0, stream>>>(nullptr, 0, w_ih, 512, b_ih, b_hh,
                                          ixp0, G4, Bc * Uc, ids, emb);
  // pipelined 2-layer recurrence (computes layer-1 input projection on the fly)
  k_rec2<<<NBR, 256, 0, stream>>>(ixp0,
                                  w_ih + (long)G4 * 512,  // wih1
                                  w_hh,                   // whh0
                                  w_hh + (long)G4 * 512,  // whh1
                                  b_ih + G4, b_hh + G4,
                                  ys2, hbuf, hO, cO, flags);
  // fc: xfc = ys2 @ fc_w.T + fc_b
  k_gemm<<<dim3(8, 7), 256, 0, stream>>>(ys2, 512, fc_w, 512, fc_b, nullptr,
                                         xfc, 512, Bc * Uc, nullptr, nullptr);
  // dec_p = xfc @ wd.T + jb1   (wd = jw1[:, 512:], row stride 1024)
  k_gemm<<<dim3(8, 7), 256, 0, stream>>>(xfc, 512, jw1 + 512, 1024, jb1, nullptr,
                                         decb, 512, Bc * Uc, nullptr, nullptr);
  // enc_p = memory @ we.T      (we = jw1[:, :512])
  k_gemm<<<dim3(8, 32), 256, 0, stream>>>(memory, 512, jw1, 1024, nullptr, nullptr,
                                          encb, 512, Bc * Tc, nullptr, nullptr);
  // fused joint
  k_joint<<<500, 512, 0, stream>>>(encb, decb, jw2, jb2, out);
}

// Round 3
// 1650.551 us; speedup vs baseline: 2.7537x; 1.1972x over previous
//
#include <hip/hip_runtime.h>

#define Bc 4
#define Tc 500
#define Uc 100
#define Vc 64
#define G4 2048

__device__ __forceinline__ float fsig(float x) {
  return __builtin_amdgcn_rcpf(1.f + __expf(-x));
}
__device__ __forceinline__ float ftanh(float x) {
  float e = __expf(2.f * x);
  return 1.f - 2.f * __builtin_amdgcn_rcpf(e + 1.f);
}

__device__ __forceinline__ unsigned ldA(const unsigned* p) {
  return __hip_atomic_load(p, __ATOMIC_RELAXED, __HIP_MEMORY_SCOPE_AGENT);
}
__device__ __forceinline__ void stA(unsigned* p, unsigned v) {
  __hip_atomic_store(p, v, __ATOMIC_RELAXED, __HIP_MEMORY_SCOPE_AGENT);
}

// ---------------- GEMM tile (shared device body) ----------------
// C[n][m] = sum_k Arow(n)[k] * Bw[m*ldb + k] + bias[m] + bias2[m], K=512.
// amode 1: row n of A lives at A + (n%100)*2048 + (n/100)*512 (h1 slot layout).
// ids != null: row n = emb[ids[n]] (stride 512).
template <int ATOMICST>
__device__ __forceinline__ void gemm_tile(
    const float* __restrict__ A, int lda, int amode,
    const float* __restrict__ Bw, int ldb,
    const float* __restrict__ bias, const float* __restrict__ bias2,
    float* __restrict__ C, int ldc, int N, int m0, int n0,
    const int* __restrict__ ids, const float* __restrict__ emb)
{
  __shared__ float As[16][65];
  __shared__ float Bs[16][65];
  const int tid = threadIdx.x;
  const int tx = tid & 15, ty = tid >> 4;
  float acc[4][4] = {};
  for (int k0 = 0; k0 < 512; k0 += 16) {
#pragma unroll
    for (int i = 0; i < 4; ++i) {
      int n = n0 + ty + 16 * i;
      float av = 0.f;
      if (n < N) {
        const float* ar = ids ? (emb + (long)ids[n] * 512)
                              : (amode ? (A + (long)(n % Uc) * G4 + (n / Uc) * 512)
                                       : (A + (long)n * lda));
        av = ar[k0 + tx];
      }
      As[tx][ty + 16 * i] = av;
      Bs[tx][ty + 16 * i] = Bw[(long)(m0 + ty + 16 * i) * ldb + k0 + tx];
    }
    __syncthreads();
#pragma unroll
    for (int kl = 0; kl < 16; ++kl) {
      float a[4], b[4];
#pragma unroll
      for (int i = 0; i < 4; ++i) a[i] = As[kl][ty * 4 + i];
#pragma unroll
      for (int j = 0; j < 4; ++j) b[j] = Bs[kl][tx * 4 + j];
#pragma unroll
      for (int i = 0; i < 4; ++i)
#pragma unroll
        for (int j = 0; j < 4; ++j) acc[i][j] += a[i] * b[j];
    }
    __syncthreads();
  }
#pragma unroll
  for (int i = 0; i < 4; ++i) {
    int n = n0 + ty * 4 + i;
    if (n >= N) continue;
#pragma unroll
    for (int j = 0; j < 4; ++j) {
      int m = m0 + tx * 4 + j;
      float v = acc[i][j];
      if (bias)  v += bias[m];
      if (bias2) v += bias2[m];
      if (ATOMICST)
        stA((unsigned*)C + (long)n * ldc + m, __float_as_uint(v));
      else
        C[(long)n * ldc + m] = v;
    }
  }
}

__global__ __launch_bounds__(256) void k_gemm(
    const float* __restrict__ A, int lda, int amode,
    const float* __restrict__ Bw, int ldb,
    const float* __restrict__ bias, const float* __restrict__ bias2,
    float* __restrict__ C, int ldc, int N)
{
  gemm_tile<0>(A, lda, amode, Bw, ldb, bias, bias2, C, ldc, N,
               blockIdx.x * 64, blockIdx.y * 64, nullptr, nullptr);
}

// ---------------- dataflow LSTM recurrence ----------------
// blk 0..31 : layer 0, 16 units each, whh0 rows (64) in VGPRs.
// blk 32..95: layer 1,  8 units each, wih1(32)+whh1(32) rows in VGPRs.
// No barriers: h0s/h1s/ixp0 are NaN-initialized write-once slot arrays;
// consumers spin on relaxed agent-scope b32 loads until bits != 0xFFFFFFFF.
__device__ void rec_path(
    const float* __restrict__ ixp0,   // (B*U, 2048), NaN-poll
    const float* __restrict__ wih1, const float* __restrict__ whh0,
    const float* __restrict__ whh1,
    const float* __restrict__ bih1, const float* __restrict__ bhh1,
    float* __restrict__ h0s,          // (100, B, 512) slots
    float* __restrict__ h1s,          // (100, B, 512) slots
    float* __restrict__ hO, float* __restrict__ cO)
{
  __shared__ float4 hl4[1024];  // [src 2][b 4][quad 128], swizzled
  __shared__ float4 red4[256];
  const int tid = threadIdx.x;
  const int blk = blockIdx.x;
  const bool isL1 = blk >= 32;
  const int rg = tid & 15, ks = tid >> 4;
  const int lane = tid & 63, wv = tid >> 6;

  // weight preload: 4 rows x 32 k (8 float4) -> 128 VGPRs
  float4 wr4[4][8];
#pragma unroll
  for (int r = 0; r < 4; ++r) {
    int lr = rg * 4 + r;
    const float* wsrc; int grow;
    if (!isL1) { int q = lr >> 4, uu = lr & 15; grow = q * 512 + blk * 16 + uu; wsrc = whh0; }
    else {
      int jb = blk - 32; int half = lr >> 5, q = (lr >> 3) & 3, uu = lr & 7;
      grow = q * 512 + jb * 8 + uu; wsrc = half ? whh1 : wih1;
    }
    const float4* wp = (const float4*)(wsrc + (long)grow * 512 + ks * 32);
#pragma unroll
    for (int jj = 0; jj < 8; ++jj) wr4[r][jj] = wp[jj];
  }

  const int nu = isL1 ? 8 : 16;
  const bool eact = tid < nu * 4;
  const int euu = tid >> 2, eb = tid & 3;
  float creg = 0.f;
  float bgate[4] = {0.f, 0.f, 0.f, 0.f};
  if (isL1 && eact) {
#pragma unroll
    for (int q = 0; q < 4; ++q) {
      int grow = q * 512 + (blk - 32) * 8 + euu;
      bgate[q] = bih1[grow] + bhh1[grow];
    }
  }

  const unsigned* h0u = (const unsigned*)h0s;
  const unsigned* h1u = (const unsigned*)h1s;
  const unsigned* ixu = (const unsigned*)ixp0;
  const int hsrc = (isL1 && rg >= 8) ? 1 : 0;
  const float* redf = (const float*)red4;

  for (int s = 0; s < Uc; ++s) {
    // ---- poll inputs (write-once slots, NaN sentinel) ----
    float ixv[4] = {0.f, 0.f, 0.f, 0.f};
    if (!isL1 && eact) {
      const unsigned* ib = ixu + ((long)(eb * Uc + s) * G4 + blk * 16 + euu);
      unsigned g0, g1, g2, g3;
      while (true) {
        g0 = ldA(ib); g1 = ldA(ib + 512); g2 = ldA(ib + 1024); g3 = ldA(ib + 1536);
        if (g0 != 0xFFFFFFFFu && g1 != 0xFFFFFFFFu &&
            g2 != 0xFFFFFFFFu && g3 != 0xFFFFFFFFu) break;
        __builtin_amdgcn_s_sleep(1);
      }
      ixv[0] = __uint_as_float(g0); ixv[1] = __uint_as_float(g1);
      ixv[2] = __uint_as_float(g2); ixv[3] = __uint_as_float(g3);
    }

    unsigned ha[8], hb[8];   // ha: primary h (L0: h0[s-1]; L1: h0[s]); hb: L1 h1[s-1]
    {
      const unsigned* pa = nullptr; const unsigned* pb = nullptr;
      if (!isL1) { if (s > 0) pa = h0u + (long)(s - 1) * G4 + tid * 4; }
      else {
        pa = h0u + (long)s * G4 + tid * 4;
        if (s > 0) pb = h1u + (long)(s - 1) * G4 + tid * 4;
      }
      bool done = false;
      while (!done) {
        bool ok = true;
        if (pa) {
#pragma unroll
          for (int it = 0; it < 2; ++it)
#pragma unroll
            for (int c = 0; c < 4; ++c) {
              unsigned u = ldA(pa + it * 1024 + c);
              ha[it * 4 + c] = u; ok &= (u != 0xFFFFFFFFu);
            }
        }
        if (pb) {
#pragma unroll
          for (int it = 0; it < 2; ++it)
#pragma unroll
            for (int c = 0; c < 4; ++c) {
              unsigned u = ldA(pb + it * 1024 + c);
              hb[it * 4 + c] = u; ok &= (u != 0xFFFFFFFFu);
            }
        }
        done = ok;
        if (!done) __builtin_amdgcn_s_sleep(1);
      }
      if (!pa) { for (int i = 0; i < 8; ++i) ha[i] = 0u; }
      if (!pb) { for (int i = 0; i < 8; ++i) hb[i] = 0u; }
    }
    // stage into LDS (rotated-quad swizzle)
#pragma unroll
    for (int it = 0; it < 2; ++it) {
      int qd = tid + it * 256;
      int b = qd >> 7, kq = qd & 127;
      int c = kq >> 3, o = kq & 7;
      int dst = b * 128 + c * 8 + ((o + c) & 7);
      hl4[dst] = make_float4(__uint_as_float(ha[it * 4 + 0]), __uint_as_float(ha[it * 4 + 1]),
                             __uint_as_float(ha[it * 4 + 2]), __uint_as_float(ha[it * 4 + 3]));
      if (isL1)
        hl4[512 + dst] = make_float4(__uint_as_float(hb[it * 4 + 0]), __uint_as_float(hb[it * 4 + 1]),
                                     __uint_as_float(hb[it * 4 + 2]), __uint_as_float(hb[it * 4 + 3]));
    }
    __syncthreads();

    // ---- dot ----
    float acc[4][4] = {};
#pragma unroll
    for (int j = 0; j < 8; ++j) {
      int pq = hsrc * 512 + ks * 8 + ((j + ks) & 7);
      float4 h0q = hl4[pq];
      float4 h1q = hl4[pq + 128];
      float4 h2q = hl4[pq + 256];
      float4 h3q = hl4[pq + 384];
#pragma unroll
      for (int r = 0; r < 4; ++r) {
        float4 w = wr4[r][j];
        acc[r][0] += w.x * h0q.x + w.y * h0q.y + w.z * h0q.z + w.w * h0q.w;
        acc[r][1] += w.x * h1q.x + w.y * h1q.y + w.z * h1q.z + w.w * h1q.w;
        acc[r][2] += w.x * h2q.x + w.y * h2q.y + w.z * h2q.z + w.w * h2q.w;
        acc[r][3] += w.x * h3q.x + w.y * h3q.y + w.z * h3q.z + w.w * h3q.w;
      }
    }
#pragma unroll
    for (int r = 0; r < 4; ++r)
#pragma unroll
      for (int b = 0; b < 4; ++b) {
        float v = acc[r][b];
        v += __shfl_xor(v, 16);
        v += __shfl_xor(v, 32);
        acc[r][b] = v;
      }
    if (lane < 16) {
#pragma unroll
      for (int r = 0; r < 4; ++r)
        red4[wv * 64 + lane * 4 + r] =
            make_float4(acc[r][0], acc[r][1], acc[r][2], acc[r][3]);
    }
    __syncthreads();

    // ---- epilogue: gates -> activations -> store h slot ----
    if (eact) {
      float gv[4];
#pragma unroll
      for (int q = 0; q < 4; ++q) {
        float sv = 0.f;
        int lrA = isL1 ? (q * 8 + euu) : (q * 16 + euu);
#pragma unroll
        for (int w = 0; w < 4; ++w) sv += redf[(w * 64 + lrA) * 4 + eb];
        if (isL1) {
          int lrB = 32 + q * 8 + euu;
#pragma unroll
          for (int w = 0; w < 4; ++w) sv += redf[(w * 64 + lrB) * 4 + eb];
          sv += bgate[q];
        } else {
          sv += ixv[q];
        }
        gv[q] = sv;
      }
      float cn = fsig(gv[1]) * creg + fsig(gv[0]) * ftanh(gv[2]);
      float hn = fsig(gv[3]) * ftanh(cn);
      creg = cn;
      int gu = (isL1 ? (blk - 32) * 8 : blk * 16) + euu;
      unsigned* dst = (unsigned*)(isL1 ? h1s : h0s) + (long)s * G4 + eb * 512 + gu;
      stA(dst, __float_as_uint(hn));
      if (s == Uc - 1) {
        hO[(isL1 ? G4 : 0) + eb * 512 + gu] = hn;
        cO[(isL1 ? G4 : 0) + eb * 512 + gu] = cn;
      }
    }
  }
}

// Fused launch: 96 rec blocks + 224 ixp0-GEMM blocks + 256 enc-GEMM blocks.
__global__ __launch_bounds__(256, 1) void k_fused(
    const int* __restrict__ ids, const float* __restrict__ emb,
    const float* __restrict__ memory,
    const float* __restrict__ w_ih, const float* __restrict__ b_ih,
    const float* __restrict__ b_hh,
    const float* __restrict__ wih1, const float* __restrict__ whh0,
    const float* __restrict__ whh1,
    const float* __restrict__ bih1, const float* __restrict__ bhh1,
    const float* __restrict__ jw1,
    float* __restrict__ ixp0, float* __restrict__ h0s, float* __restrict__ h1s,
    float* __restrict__ encb, float* __restrict__ hO, float* __restrict__ cO)
{
  const int blk = blockIdx.x;
  if (blk < 96) {
    rec_path(ixp0, wih1, whh0, whh1, bih1, bhh1, h0s, h1s, hO, cO);
  } else if (blk < 320) {
    int g = blk - 96;  // 32 m-tiles x 7 n-tiles
    gemm_tile<1>(nullptr, 0, 0, w_ih, 512, b_ih, b_hh,
                 ixp0, G4, Bc * Uc, (g % 32) * 64, (g / 32) * 64, ids, emb);
  } else {
    int g = blk - 320; // 8 m-tiles x 32 n-tiles
    gemm_tile<0>(memory, 512, 0, jw1, 1024, nullptr, nullptr,
                 encb, 512, Bc * Tc, (g & 7) * 64, (g >> 3) * 64, nullptr, nullptr);
  }
}

// ---------------- fused joint ----------------
__global__ __launch_bounds__(512) void k_joint(
    const float* __restrict__ enc,   // (B*T, 512)
    const float* __restrict__ dec,   // (B*U, 512), includes jb1
    const float* __restrict__ jw2,   // (64, 512)
    const float* __restrict__ jb2,   // (64)
    float* __restrict__ out)         // (B,T,U,64)
{
  __shared__ float th[512];
  __shared__ float red[512];
  __shared__ float el[4 * 512];
  const int tid = threadIdx.x;
  const int blk = blockIdx.x;
  const int bb = blk / 125;
  const int t0 = (blk % 125) * 4;
  const int wave = tid >> 6, lane = tid & 63;
  const int vg = lane & 7, pw = lane >> 3;
  const int kb = (wave * 8 + pw) * 8;
  float w2r[8][8];
#pragma unroll
  for (int j = 0; j < 8; ++j) {
    const float* wp = jw2 + (vg + 8 * j) * 512 + kb;
    float4 x0 = *(const float4*)wp;
    float4 x1 = *(const float4*)(wp + 4);
    w2r[j][0] = x0.x; w2r[j][1] = x0.y; w2r[j][2] = x0.z; w2r[j][3] = x0.w;
    w2r[j][4] = x1.x; w2r[j][5] = x1.y; w2r[j][6] = x1.z; w2r[j][7] = x1.w;
  }
  for (int ii = tid; ii < 4 * 512; ii += 512)
    el[ii] = enc[(long)(bb * Tc + t0 + (ii >> 9)) * 512 + (ii & 511)];
  __syncthreads();
  for (int tt = 0; tt < 4; ++tt) {
    const int t = t0 + tt;
    for (int u = 0; u < Uc; ++u) {
      th[tid] = ftanh(el[tt * 512 + tid] + dec[(long)(bb * Uc + u) * 512 + tid]);
      __syncthreads();
      float4 a0 = *(const float4*)&th[kb];
      float4 a1 = *(const float4*)&th[kb + 4];
      float acc[8];
#pragma unroll
      for (int j = 0; j < 8; ++j)
        acc[j] = w2r[j][0] * a0.x + w2r[j][1] * a0.y + w2r[j][2] * a0.z + w2r[j][3] * a0.w
               + w2r[j][4] * a1.x + w2r[j][5] * a1.y + w2r[j][6] * a1.z + w2r[j][7] * a1.w;
#pragma unroll
      for (int j = 0; j < 8; ++j) {
        acc[j] += __shfl_xor(acc[j], 8);
        acc[j] += __shfl_xor(acc[j], 16);
        acc[j] += __shfl_xor(acc[j], 32);
      }
      if (pw == 0) {
        *(float4*)&red[wave * 64 + vg * 8] = make_float4(acc[0], acc[1], acc[2], acc[3]);
        *(float4*)&red[wave * 64 + vg * 8 + 4] = make_float4(acc[4], acc[5], acc[6], acc[7]);
      }
      __syncthreads();
      if (tid < 64) {
        const int o = (tid & 7) * 8 + (tid >> 3);
        float sum = jb2[tid];
#pragma unroll
        for (int w = 0; w < 8; ++w) sum += red[w * 64 + o];
        out[(long)((bb * Tc + t) * Uc + u) * Vc + tid] = sum;
      }
      __syncthreads();
    }
  }
}

extern "C" void kernel_launch(void* const* d_in, const int* in_sizes, int n_in,
                              void* d_out, int out_size, void* d_ws, size_t ws_size,
                              hipStream_t stream)
{
  const int*   ids    = (const int*)d_in[0];
  const float* memory = (const float*)d_in[1];
  const float* emb    = (const float*)d_in[2];
  const float* w_ih   = (const float*)d_in[3];
  const float* w_hh   = (const float*)d_in[4];
  const float* b_ih   = (const float*)d_in[5];
  const float* b_hh   = (const float*)d_in[6];
  const float* fc_w   = (const float*)d_in[7];
  const float* fc_b   = (const float*)d_in[8];
  const float* jw1    = (const float*)d_in[9];
  const float* jb1    = (const float*)d_in[10];
  const float* jw2    = (const float*)d_in[11];
  const float* jb2    = (const float*)d_in[12];
  float* out = (float*)d_out;

  float* wsf  = (float*)d_ws;
  // layout (floats): [ixp0 819200 | h0s 204800 | h1s 204800 | encb 1024000]
  // after the fused kernel, ixp0 region is reused: [xfc 204800 | decb 204800]
  float* ixp0 = wsf;
  float* xfc  = wsf;
  float* decb = wsf + 204800;
  float* h0s  = wsf + 819200;
  float* h1s  = wsf + 1024000;
  float* encb = wsf + 1228800;

  float* hO = out + (long)Bc * Tc * Uc * Vc;
  float* cO = hO + 2 * Bc * 512;

  // NaN-init all dataflow slots (ixp0 + h0s + h1s) each call.
  hipMemsetAsync(d_ws, 0xFF, (size_t)1228800 * 4, stream);

  // recurrence + ixp0 projection + enc projection, one launch
  k_fused<<<576, 256, 0, stream>>>(ids, emb, memory,
                                   w_ih, b_ih, b_hh,
                                   w_ih + (long)G4 * 512,  // wih1
                                   w_hh,                   // whh0
                                   w_hh + (long)G4 * 512,  // whh1
                                   b_ih + G4, b_hh + G4,
                                   jw1,
                                   ixp0, h0s, h1s, encb, hO, cO);
  // fc: xfc = h1slots @ fc_w.T + fc_b   (amode=1 reads slot layout)
  k_gemm<<<dim3(8, 7), 256, 0, stream>>>(h1s, 0, 1, fc_w, 512, fc_b, nullptr,
                                         xfc, 512, Bc * Uc);
  // dec = xfc @ wd.T + jb1   (wd = jw1[:, 512:], row stride 1024)
  k_gemm<<<dim3(8, 7), 256, 0, stream>>>(xfc, 512, 0, jw1 + 512, 1024, jb1, nullptr,
                                         decb, 512, Bc * Uc);
  // fused joint
  k_joint<<<500, 512, 0, stream>>>(encb, decb, jw2, jb2, out);
}

// Round 4
// 1148.167 us; speedup vs baseline: 3.9586x; 1.4376x over previous
//
#include <hip/hip_runtime.h>

#define Bc 4
#define Tc 500
#define Uc 100
#define Vc 64
#define G4 2048

__device__ __forceinline__ float fsig(float x) {
  return __builtin_amdgcn_rcpf(1.f + __expf(-x));
}
__device__ __forceinline__ float ftanh(float x) {
  float e = __expf(2.f * x);
  return 1.f - 2.f * __builtin_amdgcn_rcpf(e + 1.f);
}

__device__ __forceinline__ unsigned ldA(const unsigned* p) {
  return __hip_atomic_load(p, __ATOMIC_RELAXED, __HIP_MEMORY_SCOPE_AGENT);
}
__device__ __forceinline__ void stA(unsigned* p, unsigned v) {
  __hip_atomic_store(p, v, __ATOMIC_RELAXED, __HIP_MEMORY_SCOPE_AGENT);
}

// ---------------- generic GEMM tile ----------------
// C[n][m] = sum_k Arow(n)[k] * Bw[m*ldb + k] (+bias+bias2), K=512.
// ids != null: row n = emb[ids[n]].
template <int ATOMICST>
__device__ __forceinline__ void gemm_tile(
    const float* __restrict__ A, int lda,
    const float* __restrict__ Bw, int ldb,
    const float* __restrict__ bias, const float* __restrict__ bias2,
    float* __restrict__ C, int ldc, int N, int m0, int n0,
    const int* __restrict__ ids, const float* __restrict__ emb)
{
  __shared__ float As[16][65];
  __shared__ float Bs[16][65];
  const int tid = threadIdx.x;
  const int tx = tid & 15, ty = tid >> 4;
  float acc[4][4] = {};
  for (int k0 = 0; k0 < 512; k0 += 16) {
#pragma unroll
    for (int i = 0; i < 4; ++i) {
      int n = n0 + ty + 16 * i;
      float av = 0.f;
      if (n < N) {
        const float* ar = ids ? (emb + (long)ids[n] * 512) : (A + (long)n * lda);
        av = ar[k0 + tx];
      }
      As[tx][ty + 16 * i] = av;
      Bs[tx][ty + 16 * i] = Bw[(long)(m0 + ty + 16 * i) * ldb + k0 + tx];
    }
    __syncthreads();
#pragma unroll
    for (int kl = 0; kl < 16; ++kl) {
      float a[4], b[4];
#pragma unroll
      for (int i = 0; i < 4; ++i) a[i] = As[kl][ty * 4 + i];
#pragma unroll
      for (int j = 0; j < 4; ++j) b[j] = Bs[kl][tx * 4 + j];
#pragma unroll
      for (int i = 0; i < 4; ++i)
#pragma unroll
        for (int j = 0; j < 4; ++j) acc[i][j] += a[i] * b[j];
    }
    __syncthreads();
  }
#pragma unroll
  for (int i = 0; i < 4; ++i) {
    int n = n0 + ty * 4 + i;
    if (n >= N) continue;
#pragma unroll
    for (int j = 0; j < 4; ++j) {
      int m = m0 + tx * 4 + j;
      float v = acc[i][j];
      if (bias)  v += bias[m];
      if (bias2) v += bias2[m];
      if (ATOMICST)
        stA((unsigned*)C + (long)n * ldc + m, __float_as_uint(v));
      else
        C[(long)n * ldc + m] = v;
    }
  }
}

// ---------------- wdc tile: wdc[h][e] = sum_d wd[h][d]*fc_w[d][e] ----------------
// wd[h][d] = jw1[h*1024 + 512 + d]; B non-transposed (B[d][e] = fc_w[d*512+e]).
__device__ void wdc_tile(const float* __restrict__ jw1,
                         const float* __restrict__ fc_w,
                         float* __restrict__ wdc, int n0, int m0)
{
  __shared__ float As[16][65];
  __shared__ float Bs[16][65];
  const int tid = threadIdx.x;
  const int tx = tid & 15, ty = tid >> 4;
  float acc[4][4] = {};
  for (int k0 = 0; k0 < 512; k0 += 16) {
#pragma unroll
    for (int i = 0; i < 4; ++i) {
      As[tx][ty + 16 * i] = jw1[(long)(n0 + ty + 16 * i) * 1024 + 512 + k0 + tx];
      Bs[ty][tx + 16 * i] = fc_w[(long)(k0 + ty) * 512 + m0 + tx + 16 * i];
    }
    __syncthreads();
#pragma unroll
    for (int kl = 0; kl < 16; ++kl) {
      float a[4], b[4];
#pragma unroll
      for (int i = 0; i < 4; ++i) a[i] = As[kl][ty * 4 + i];
#pragma unroll
      for (int j = 0; j < 4; ++j) b[j] = Bs[kl][tx * 4 + j];
#pragma unroll
      for (int i = 0; i < 4; ++i)
#pragma unroll
        for (int j = 0; j < 4; ++j) acc[i][j] += a[i] * b[j];
    }
    __syncthreads();
  }
#pragma unroll
  for (int i = 0; i < 4; ++i)
#pragma unroll
    for (int j = 0; j < 4; ++j)
      stA((unsigned*)wdc + (long)(n0 + ty * 4 + i) * 512 + m0 + tx * 4 + j,
          __float_as_uint(acc[i][j]));
}

// ---------------- dec tile (flag-gated, ldA+NaN backstop) ----------------
// dec[n][h] = sum_e h1s(row n)[e] * wdc[h][e] + bdc[h]; n=(b,u), N=400.
__device__ void dec_tile(const float* __restrict__ h1s, const float* __restrict__ wdc,
                         const float* __restrict__ jw1, const float* __restrict__ fc_b,
                         const float* __restrict__ jb1, float* __restrict__ decb,
                         const int* __restrict__ f1, int m0, int n0)
{
  __shared__ float As[16][65];
  __shared__ float Bs[16][65];
  __shared__ float biasl[64];
  const int tid = threadIdx.x;
  const int tx = tid & 15, ty = tid >> 4;
  int u_hi = 0;
  for (int rr = 0; rr < 64; ++rr) {
    int r = n0 + rr;
    if (r < 400) { int u = r % Uc; u_hi = max(u_hi, u + 1); }
  }
  if (tid < 64)
    while ((int)ldA((const unsigned*)(f1 + tid * 16)) < u_hi)
      __builtin_amdgcn_s_sleep(8);
  if (tid < 64) {
    int m = m0 + tid;
    const float4* wp = (const float4*)(jw1 + (long)m * 1024 + 512);
    const float4* fb = (const float4*)fc_b;
    float bb = jb1[m];
#pragma unroll 8
    for (int d4 = 0; d4 < 128; ++d4) {
      float4 w = wp[d4], f = fb[d4];
      bb += w.x * f.x + w.y * f.y + w.z * f.z + w.w * f.w;
    }
    biasl[tid] = bb;
  }
  __syncthreads();
  const unsigned* h1u = (const unsigned*)h1s;
  const unsigned* wdu = (const unsigned*)wdc;
  float acc[4][4] = {};
  for (int k0 = 0; k0 < 512; k0 += 16) {
    unsigned uA[4], uB[4];
#pragma unroll
    for (int i = 0; i < 4; ++i) {
      int n = n0 + ty + 16 * i;
      uA[i] = (n < 400) ? ldA(h1u + (long)(n % Uc) * G4 + (n / Uc) * 512 + k0 + tx) : 0u;
      uB[i] = ldA(wdu + (long)(m0 + ty + 16 * i) * 512 + k0 + tx);
    }
#pragma unroll
    for (int i = 0; i < 4; ++i) {
      int n = n0 + ty + 16 * i;
      while (uA[i] == 0xFFFFFFFFu)
        uA[i] = ldA(h1u + (long)(n % Uc) * G4 + (n / Uc) * 512 + k0 + tx);
      while (uB[i] == 0xFFFFFFFFu)
        uB[i] = ldA(wdu + (long)(m0 + ty + 16 * i) * 512 + k0 + tx);
      As[tx][ty + 16 * i] = __uint_as_float(uA[i]);
      Bs[tx][ty + 16 * i] = __uint_as_float(uB[i]);
    }
    __syncthreads();
#pragma unroll
    for (int kl = 0; kl < 16; ++kl) {
      float a[4], b[4];
#pragma unroll
      for (int i = 0; i < 4; ++i) a[i] = As[kl][ty * 4 + i];
#pragma unroll
      for (int j = 0; j < 4; ++j) b[j] = Bs[kl][tx * 4 + j];
#pragma unroll
      for (int i = 0; i < 4; ++i)
#pragma unroll
        for (int j = 0; j < 4; ++j) acc[i][j] += a[i] * b[j];
    }
    __syncthreads();
  }
#pragma unroll
  for (int i = 0; i < 4; ++i) {
    int n = n0 + ty * 4 + i;
    if (n >= 400) continue;
#pragma unroll
    for (int j = 0; j < 4; ++j)
      decb[(long)n * 512 + m0 + tx * 4 + j] = acc[i][j] + biasl[tx * 4 + j];
  }
}

// ---------------- dataflow LSTM recurrence (flag-gated) ----------------
__device__ void rec_path(
    const float* __restrict__ ixp0,
    const float* __restrict__ wih1, const float* __restrict__ whh0,
    const float* __restrict__ whh1,
    const float* __restrict__ bih1, const float* __restrict__ bhh1,
    float* __restrict__ h0s, float* __restrict__ h1s,
    float* __restrict__ hO, float* __restrict__ cO, int* __restrict__ flags)
{
  __shared__ float4 hl4[1024];
  __shared__ float4 red4[256];
  const int tid = threadIdx.x;
  const int blk = blockIdx.x;
  const bool isL1 = blk >= 32;
  const int rg = tid & 15, ks = tid >> 4;
  const int lane = tid & 63, wv = tid >> 6;
  const int* f0 = flags;
  const int* f1 = flags + 512;
  unsigned* myflag = (unsigned*)(isL1 ? (f1 + (blk - 32) * 16) : (f0 + blk * 16));

  float4 wr4[4][8];
#pragma unroll
  for (int r = 0; r < 4; ++r) {
    int lr = rg * 4 + r;
    const float* wsrc; int grow;
    if (!isL1) { int q = lr >> 4, uu = lr & 15; grow = q * 512 + blk * 16 + uu; wsrc = whh0; }
    else {
      int jb = blk - 32; int half = lr >> 5, q = (lr >> 3) & 3, uu = lr & 7;
      grow = q * 512 + jb * 8 + uu; wsrc = half ? whh1 : wih1;
    }
    const float4* wp = (const float4*)(wsrc + (long)grow * 512 + ks * 32);
#pragma unroll
    for (int jj = 0; jj < 8; ++jj) wr4[r][jj] = wp[jj];
  }

  const int nu = isL1 ? 8 : 16;
  const bool eact = tid < nu * 4;
  const int euu = tid >> 2, eb = tid & 3;
  float creg = 0.f;
  float bgate[4] = {0.f, 0.f, 0.f, 0.f};
  if (isL1 && eact) {
#pragma unroll
    for (int q = 0; q < 4; ++q) {
      int grow = q * 512 + (blk - 32) * 8 + euu;
      bgate[q] = bih1[grow] + bhh1[grow];
    }
  }

  const unsigned* h0u = (const unsigned*)h0s;
  const unsigned* h1u = (const unsigned*)h1s;
  const unsigned* ixu = (const unsigned*)ixp0;
  const int hsrc = (isL1 && rg >= 8) ? 1 : 0;
  const float* redf = (const float*)red4;

  for (int s = 0; s < Uc; ++s) {
    float ixv[4] = {0.f, 0.f, 0.f, 0.f};
    if (wv == 0) {
      // ixp NaN-poll (L0 epilogue threads; feed-latency wait at small s)
      if (!isL1 && eact) {
        const unsigned* ib = ixu + ((long)(eb * Uc + s) * G4 + blk * 16 + euu);
        unsigned g0, g1, g2, g3;
        while (true) {
          g0 = ldA(ib); g1 = ldA(ib + 512); g2 = ldA(ib + 1024); g3 = ldA(ib + 1536);
          if (g0 != 0xFFFFFFFFu && g1 != 0xFFFFFFFFu &&
              g2 != 0xFFFFFFFFu && g3 != 0xFFFFFFFFu) break;
          __builtin_amdgcn_s_sleep(1);
        }
        ixv[0] = __uint_as_float(g0); ixv[1] = __uint_as_float(g1);
        ixv[2] = __uint_as_float(g2); ixv[3] = __uint_as_float(g3);
      }
      // flag poll (one wave, 64B-strided flag words)
      if (!isL1) {
        if (s > 0 && lane < 32)
          while ((int)ldA((const unsigned*)(f0 + lane * 16)) < s)
            __builtin_amdgcn_s_sleep(2);
      } else {
        if (lane < 32)
          while ((int)ldA((const unsigned*)(f0 + lane * 16)) < s + 1)
            __builtin_amdgcn_s_sleep(2);
        if (s > 0)
          while ((int)ldA((const unsigned*)(f1 + lane * 16)) < s)
            __builtin_amdgcn_s_sleep(2);
      }
    }
    __syncthreads();

    // gathered data loads + NaN backstop
    unsigned ha[8], hb[8];
    {
      const unsigned* pa = nullptr; const unsigned* pb = nullptr;
      if (!isL1) { if (s > 0) pa = h0u + (long)(s - 1) * G4 + tid * 4; }
      else {
        pa = h0u + (long)s * G4 + tid * 4;
        if (s > 0) pb = h1u + (long)(s - 1) * G4 + tid * 4;
      }
      bool done = false;
      while (!done) {
        bool ok = true;
        if (pa) {
#pragma unroll
          for (int it = 0; it < 2; ++it)
#pragma unroll
            for (int c = 0; c < 4; ++c) {
              unsigned u = ldA(pa + it * 1024 + c);
              ha[it * 4 + c] = u; ok &= (u != 0xFFFFFFFFu);
            }
        }
        if (pb) {
#pragma unroll
          for (int it = 0; it < 2; ++it)
#pragma unroll
            for (int c = 0; c < 4; ++c) {
              unsigned u = ldA(pb + it * 1024 + c);
              hb[it * 4 + c] = u; ok &= (u != 0xFFFFFFFFu);
            }
        }
        done = ok;
        if (!done) __builtin_amdgcn_s_sleep(1);
      }
      if (!pa) { for (int i = 0; i < 8; ++i) ha[i] = 0u; }
      if (!pb) { for (int i = 0; i < 8; ++i) hb[i] = 0u; }
    }
#pragma unroll
    for (int it = 0; it < 2; ++it) {
      int qd = tid + it * 256;
      int b = qd >> 7, kq = qd & 127;
      int c = kq >> 3, o = kq & 7;
      int dst = b * 128 + c * 8 + ((o + c) & 7);
      hl4[dst] = make_float4(__uint_as_float(ha[it * 4 + 0]), __uint_as_float(ha[it * 4 + 1]),
                             __uint_as_float(ha[it * 4 + 2]), __uint_as_float(ha[it * 4 + 3]));
      if (isL1)
        hl4[512 + dst] = make_float4(__uint_as_float(hb[it * 4 + 0]), __uint_as_float(hb[it * 4 + 1]),
                                     __uint_as_float(hb[it * 4 + 2]), __uint_as_float(hb[it * 4 + 3]));
    }
    __syncthreads();

    float acc[4][4] = {};
#pragma unroll
    for (int j = 0; j < 8; ++j) {
      int pq = hsrc * 512 + ks * 8 + ((j + ks) & 7);
      float4 h0q = hl4[pq];
      float4 h1q = hl4[pq + 128];
      float4 h2q = hl4[pq + 256];
      float4 h3q = hl4[pq + 384];
#pragma unroll
      for (int r = 0; r < 4; ++r) {
        float4 w = wr4[r][j];
        acc[r][0] += w.x * h0q.x + w.y * h0q.y + w.z * h0q.z + w.w * h0q.w;
        acc[r][1] += w.x * h1q.x + w.y * h1q.y + w.z * h1q.z + w.w * h1q.w;
        acc[r][2] += w.x * h2q.x + w.y * h2q.y + w.z * h2q.z + w.w * h2q.w;
        acc[r][3] += w.x * h3q.x + w.y * h3q.y + w.z * h3q.z + w.w * h3q.w;
      }
    }
#pragma unroll
    for (int r = 0; r < 4; ++r)
#pragma unroll
      for (int b = 0; b < 4; ++b) {
        float v = acc[r][b];
        v += __shfl_xor(v, 16);
        v += __shfl_xor(v, 32);
        acc[r][b] = v;
      }
    if (lane < 16) {
#pragma unroll
      for (int r = 0; r < 4; ++r)
        red4[wv * 64 + lane * 4 + r] =
            make_float4(acc[r][0], acc[r][1], acc[r][2], acc[r][3]);
    }
    __syncthreads();

    if (eact) {
      float gv[4];
#pragma unroll
      for (int q = 0; q < 4; ++q) {
        float sv = 0.f;
        int lrA = isL1 ? (q * 8 + euu) : (q * 16 + euu);
#pragma unroll
        for (int w = 0; w < 4; ++w) sv += redf[(w * 64 + lrA) * 4 + eb];
        if (isL1) {
          int lrB = 32 + q * 8 + euu;
#pragma unroll
          for (int w = 0; w < 4; ++w) sv += redf[(w * 64 + lrB) * 4 + eb];
          sv += bgate[q];
        } else {
          sv += ixv[q];
        }
        gv[q] = sv;
      }
      float cn = fsig(gv[1]) * creg + fsig(gv[0]) * ftanh(gv[2]);
      float hn = fsig(gv[3]) * ftanh(cn);
      creg = cn;
      int gu = (isL1 ? (blk - 32) * 8 : blk * 16) + euu;
      unsigned* dst = (unsigned*)(isL1 ? h1s : h0s) + (long)s * G4 + eb * 512 + gu;
      stA(dst, __float_as_uint(hn));
      if (s == Uc - 1) {
        hO[(isL1 ? G4 : 0) + eb * 512 + gu] = hn;
        cO[(isL1 ? G4 : 0) + eb * 512 + gu] = cn;
      }
    }
    // drain data stores (vmcnt(0) at barrier), then publish flag
    __syncthreads();
    if (tid == 0) stA(myflag, (unsigned)(s + 1));
  }
}

// ---------------- fused launch ----------------
// blk 0..95 rec | 96..319 ixp tiles | 320..383 wdc | 384..639 enc | 640..695 dec
__global__ __launch_bounds__(256, 1) void k_fused(
    const int* __restrict__ ids, const float* __restrict__ emb,
    const float* __restrict__ memory,
    const float* __restrict__ w_ih, const float* __restrict__ b_ih,
    const float* __restrict__ b_hh,
    const float* __restrict__ wih1, const float* __restrict__ whh0,
    const float* __restrict__ whh1,
    const float* __restrict__ bih1, const float* __restrict__ bhh1,
    const float* __restrict__ jw1, const float* __restrict__ jb1,
    const float* __restrict__ fc_w, const float* __restrict__ fc_b,
    float* __restrict__ ixp0, float* __restrict__ h0s, float* __restrict__ h1s,
    float* __restrict__ wdc, float* __restrict__ decb, float* __restrict__ encb,
    float* __restrict__ hO, float* __restrict__ cO, int* __restrict__ flags)
{
  const int blk = blockIdx.x;
  if (blk < 96) {
    rec_path(ixp0, wih1, whh0, whh1, bih1, bhh1, h0s, h1s, hO, cO, flags);
  } else if (blk < 320) {
    static const int nt_ord[7] = {0, 1, 3, 4, 2, 5, 6};
    int g = blk - 96;
    gemm_tile<1>(nullptr, 0, w_ih, 512, b_ih, b_hh,
                 ixp0, G4, Bc * Uc, (g % 32) * 64, nt_ord[g / 32] * 64, ids, emb);
  } else if (blk < 384) {
    int g = blk - 320;
    wdc_tile(jw1, fc_w, wdc, (g & 7) * 64, (g >> 3) * 64);
  } else if (blk < 640) {
    int g = blk - 384;
    gemm_tile<0>(memory, 512, jw1, 1024, nullptr, nullptr,
                 encb, 512, Bc * Tc, (g & 7) * 64, (g >> 3) * 64, nullptr, nullptr);
  } else {
    int g = blk - 640;
    dec_tile(h1s, wdc, jw1, fc_b, jb1, decb, flags + 512, (g & 7) * 64, (g >> 3) * 64);
  }
}

// ---------------- joint as GEMM with fused tanh A-operand ----------------
// out[n][v] = sum_h tanh(enc[n/100][h] + dec[b*100+u][h]) * jw2[v][h] + jb2[v]
__global__ __launch_bounds__(256) void k_joint2(
    const float* __restrict__ enc, const float* __restrict__ dec,
    const float* __restrict__ jw2, const float* __restrict__ jb2,
    float* __restrict__ out)
{
  __shared__ float As[16][65];
  __shared__ float Bs[16][65];
  const int tid = threadIdx.x;
  const int tx = tid & 15, ty = tid >> 4;
  const int n0 = blockIdx.x * 64;
  const float* erow[4];
  const float* drow[4];
#pragma unroll
  for (int i = 0; i < 4; ++i) {
    int n = n0 + ty + 16 * i;
    int u = n % Uc, bt = n / Uc, b = n / (Tc * Uc);
    erow[i] = enc + (long)bt * 512;
    drow[i] = dec + (long)(b * Uc + u) * 512;
  }
  float acc[4][4] = {};
  for (int k0 = 0; k0 < 512; k0 += 16) {
#pragma unroll
    for (int i = 0; i < 4; ++i) {
      As[tx][ty + 16 * i] = ftanh(erow[i][k0 + tx] + drow[i][k0 + tx]);
      Bs[tx][ty + 16 * i] = jw2[(long)(ty + 16 * i) * 512 + k0 + tx];
    }
    __syncthreads();
#pragma unroll
    for (int kl = 0; kl < 16; ++kl) {
      float a[4], b[4];
#pragma unroll
      for (int i = 0; i < 4; ++i) a[i] = As[kl][ty * 4 + i];
#pragma unroll
      for (int j = 0; j < 4; ++j) b[j] = Bs[kl][tx * 4 + j];
#pragma unroll
      for (int i = 0; i < 4; ++i)
#pragma unroll
        for (int j = 0; j < 4; ++j) acc[i][j] += a[i] * b[j];
    }
    __syncthreads();
  }
#pragma unroll
  for (int i = 0; i < 4; ++i) {
    long n = n0 + ty * 4 + i;
#pragma unroll
    for (int j = 0; j < 4; ++j)
      out[n * 64 + tx * 4 + j] = acc[i][j] + jb2[tx * 4 + j];
  }
}

extern "C" void kernel_launch(void* const* d_in, const int* in_sizes, int n_in,
                              void* d_out, int out_size, void* d_ws, size_t ws_size,
                              hipStream_t stream)
{
  const int*   ids    = (const int*)d_in[0];
  const float* memory = (const float*)d_in[1];
  const float* emb    = (const float*)d_in[2];
  const float* w_ih   = (const float*)d_in[3];
  const float* w_hh   = (const float*)d_in[4];
  const float* b_ih   = (const float*)d_in[5];
  const float* b_hh   = (const float*)d_in[6];
  const float* fc_w   = (const float*)d_in[7];
  const float* fc_b   = (const float*)d_in[8];
  const float* jw1    = (const float*)d_in[9];
  const float* jb1    = (const float*)d_in[10];
  const float* jw2    = (const float*)d_in[11];
  const float* jb2    = (const float*)d_in[12];
  float* out = (float*)d_out;

  float* wsf = (float*)d_ws;
  // float offsets in ws:
  int*   flags = (int*)d_ws;                 // [0, 2048)   flag words (64B-strided)
  float* ixp0  = wsf + 2048;                 // 819200
  float* h0s   = wsf + 821248;               // 204800
  float* h1s   = wsf + 1026048;              // 204800
  float* wdc   = wsf + 1230848;              // 262144
  float* decb  = wsf + 1492992;              // 204800
  float* encb  = wsf + 1697792;              // 1024000  (end 2721792 floats ~10.9MB)

  float* hO = out + (long)Bc * Tc * Uc * Vc;
  float* cO = hO + 2 * Bc * 512;

  // flags = 0; NaN-init all in-dispatch dataflow regions (ixp0,h0s,h1s,wdc)
  hipMemsetAsync(flags, 0, 2048 * 4, stream);
  hipMemsetAsync(ixp0, 0xFF, (size_t)(1492992 - 2048) * 4, stream);

  k_fused<<<696, 256, 0, stream>>>(ids, emb, memory,
                                   w_ih, b_ih, b_hh,
                                   w_ih + (long)G4 * 512,  // wih1
                                   w_hh,                   // whh0
                                   w_hh + (long)G4 * 512,  // whh1
                                   b_ih + G4, b_hh + G4,
                                   jw1, jb1, fc_w, fc_b,
                                   ixp0, h0s, h1s, wdc, decb, encb,
                                   hO, cO, flags);

  k_joint2<<<3125, 256, 0, stream>>>(encb, decb, jw2, jb2, out);
}